// Round 4
// baseline (829.075 us; speedup 1.0000x reference)
//
#include <hip/hip_runtime.h>

// ---------------------------------------------------------------------------
// GQA attention block: QKV proj -> RoPE -> causal GQA flash attention -> out proj
// B=2 S=2048 D=4096 NH=32 NKV=8 HD=128 (QKV_DIM=6144)
// R7: attention restructured: QBLK=128 with 8 waves (512 thr, lb(512,4) ->
//     2 blocks/CU), halved per-thread K/V staging, grid order (qb,bh) for L2
//     K/V reuse, wave-uniform skip of fully-masked upper 32-key half at the
//     causal diagonal. rope_kernel vectorized (bf16x8 + f32x4 table loads).
//     GEMMs unchanged from R6 (QKV 128x384 2-even-round, out-proj 256x256).
// ---------------------------------------------------------------------------

typedef __bf16 bf16;
typedef bf16 bf16x8 __attribute__((ext_vector_type(8)));
typedef bf16 bf16x4 __attribute__((ext_vector_type(4)));
typedef float f32x4 __attribute__((ext_vector_type(4)));
typedef unsigned int u32;
typedef u32 u32x4 __attribute__((ext_vector_type(4)));

#define B_ 2
#define S_ 2048
#define DM 4096
#define NH 32
#define NKV 8
#define HD 128
#define QKV_DIM 6144

typedef __attribute__((address_space(3))) void lds_void;
typedef const __attribute__((address_space(1))) void glb_void;

__device__ __forceinline__ void gld_lds16(const bf16* g, bf16* l) {
  __builtin_amdgcn_global_load_lds((glb_void*)g, (lds_void*)l, 16, 0, 0);
}

__device__ __forceinline__ u32 bf16bits(float x) {
  union { bf16 h; unsigned short s; } u;
  u.h = (bf16)x;
  return (u32)u.s;
}

#define BAR() __builtin_amdgcn_s_barrier()
#define VM4() asm volatile("s_waitcnt vmcnt(4)" ::: "memory")
#define VM0() asm volatile("s_waitcnt vmcnt(0)" ::: "memory")
#define PRIO1() __builtin_amdgcn_s_setprio(1)
#define PRIO0() __builtin_amdgcn_s_setprio(0)

// ---------------- cast fp32 -> bf16 (hidden states) ----------------
__global__ __launch_bounds__(256) void cast_f32_bf16(const float* __restrict__ src,
                                                     bf16* __restrict__ dst, int n) {
  int i = (blockIdx.x * 256 + threadIdx.x) * 4;
  float4 v = *(const float4*)(src + i);
  bf16x4 o;
  o[0] = (bf16)v.x; o[1] = (bf16)v.y; o[2] = (bf16)v.z; o[3] = (bf16)v.w;
  *(bf16x4*)(dst + i) = o;
}

// ---------------- transpose + cast weights: W[K][N] f32 -> Wt[N][K] bf16 ----
__global__ __launch_bounds__(256) void transpose_cast_w(const float* __restrict__ W,
                                                        bf16* __restrict__ Wt,
                                                        int K, int N) {
  __shared__ float tile[64][65];
  const int n0 = blockIdx.x * 64, k0 = blockIdx.y * 64;
  const int t = threadIdx.x, j = t & 63, i0 = t >> 6;
  for (int p = 0; p < 16; ++p) {
    int i = i0 + p * 4;
    tile[i][j] = W[(size_t)(k0 + i) * N + n0 + j];
  }
  __syncthreads();
  for (int p = 0; p < 16; ++p) {
    int n = i0 + p * 4;
    Wt[(size_t)(n0 + n) * K + k0 + j] = (bf16)tile[j][n];
  }
}

// ---------------- transpose V out of qkv: v_t[b][kv][d][s] ----------------
__global__ __launch_bounds__(256) void transpose_v(const bf16* __restrict__ qkv,
                                                   bf16* __restrict__ v_t) {
  __shared__ bf16 tile[64][65];
  const int s0 = blockIdx.x * 64;
  const int d0 = blockIdx.y * 64;
  const int bk = blockIdx.z;            // b*8+kv
  const int b = bk >> 3, kv = bk & 7;
  const int t = threadIdx.x, j = t & 63, i0 = t >> 6;
  const bf16* src = qkv + (size_t)b * S_ * QKV_DIM + 5120 + kv * HD;  // v offset 5120
  for (int p = 0; p < 16; ++p) {
    int i = i0 + p * 4;
    tile[i][j] = src[(size_t)(s0 + i) * QKV_DIM + d0 + j];
  }
  __syncthreads();
  bf16* dst = v_t + ((size_t)bk * HD + d0) * S_ + s0;
  for (int p = 0; p < 16; ++p) {
    int dd = i0 + p * 4;
    dst[(size_t)dd * S_ + j] = tile[j][dd];
  }
}

// ---------------- RoPE + repack q,k (vectorized; q pre-scaled) -------------
// 320 threads: 40 heads x 8 d-granules of 8. Thread handles d in [g,g+8) and
// [g+64,g+72) (rotate_half pairs). Waves 0-3 = q heads, wave 4 = k heads
// (branch is wave-uniform).
__global__ __launch_bounds__(320) void rope_kernel(const bf16* __restrict__ qkv,
                                                   const float* __restrict__ cosT,
                                                   const float* __restrict__ sinT,
                                                   bf16* __restrict__ q_r,
                                                   bf16* __restrict__ k_r) {
  const int bs = blockIdx.x;            // b*S + s
  const int b = bs >> 11, s = bs & 2047;
  const int t = threadIdx.x;
  const int hh = t >> 3;                // 0..39 (q heads then k heads)
  const int g = (t & 7) * 8;            // lower-half d-granule base
  const bool isQ = hh < NH;
  const bf16* row = qkv + (size_t)bs * QKV_DIM + (isQ ? hh * HD : DM + (hh - NH) * HD);
  bf16x8 xl8 = *(const bf16x8*)(row + g);
  bf16x8 xh8 = *(const bf16x8*)(row + g + 64);
  const float* cbase = cosT + (size_t)s * HD;
  const float* sbase = sinT + (size_t)s * HD;
  float cl[8], sl[8], ch[8], sh[8];
  *(float4*)(cl) = *(const float4*)(cbase + g);
  *(float4*)(cl + 4) = *(const float4*)(cbase + g + 4);
  *(float4*)(ch) = *(const float4*)(cbase + g + 64);
  *(float4*)(ch + 4) = *(const float4*)(cbase + g + 68);
  *(float4*)(sl) = *(const float4*)(sbase + g);
  *(float4*)(sl + 4) = *(const float4*)(sbase + g + 4);
  *(float4*)(sh) = *(const float4*)(sbase + g + 64);
  *(float4*)(sh + 4) = *(const float4*)(sbase + g + 68);
  const float scale = isQ ? 0.08838834764831845f : 1.0f;  // 1/sqrt(128) for q
  bf16x8 ol8, oh8;
#pragma unroll
  for (int j = 0; j < 8; ++j) {
    const float xl = (float)xl8[j], xh = (float)xh8[j];
    ol8[j] = (bf16)((xl * cl[j] - xh * sl[j]) * scale);
    oh8[j] = (bf16)((xh * ch[j] + xl * sh[j]) * scale);
  }
  bf16* dst = isQ ? (q_r + (((size_t)(b * NH + hh)) * S_ + s) * HD)
                  : (k_r + (((size_t)(b * NKV + (hh - NH))) * S_ + s) * HD);
  *(bf16x8*)(dst + g) = ol8;
  *(bf16x8*)(dst + g + 64) = oh8;
}

// ---------------- GEMM: C[M][N] = A[M][K] * Bt[N][K]^T  (BM x BN tiles) -----
// 512 threads = 8 waves (2 Mrows x 4 Ncols), per-wave output (BM/2)x(BN/4).
// BK=64 as two K-halves; per buffer: A[2kh][BM][32] + B[2kh][BN][32] bf16 =
// 64 KiB; double-buffered = 128 KiB. Stage group (one kh of A+B) is always
// (BM+BN)/128 = 4 global_load_lds calls/wave -> VM4 counting identical for
// both tilings. Schedule = R5's verified skeleton: BAR; read kh0 frags;
// stage t+1-kh1 -> P^1; MFMA kh0; read kh1 frags; BAR; stage t+2-kh0 -> P;
// MFMA kh1; VM4 (retires all of t+1's calls, leaves t+2-kh0 in flight).
template <bool OUT_BF16, int BM, int BN>
__global__ __launch_bounds__(512, 2) void gemm_bt(const bf16* __restrict__ A,
                                                  const bf16* __restrict__ Bt,
                                                  void* __restrict__ Cout,
                                                  int M, int N, int K) {
  constexpr int MF = BM / 32;           // m-frags per wave
  constexpr int NF = BN / 64;           // n-frags per wave
  constexpr int NCA = BM / 128;         // A stage calls per kh per wave
  constexpr int NCB = BN / 128;         // B stage calls per kh per wave
  constexpr int AKH = BM * 64;          // bytes per A kh region
  constexpr int BKH = BN * 64;          // bytes per B kh region
  constexpr int BUF = 2 * (AKH + BKH);  // 65536 for both tilings
  extern __shared__ char lds[];
  const int NT = K >> 6;                // K-tiles of 64 (K=4096 -> 64, even)

  // bijective XCD swizzle (grids are multiples of 8)
  const int nwg = gridDim.x;
  const int cpx = nwg >> 3;
  const int wg = (blockIdx.x & 7) * cpx + (blockIdx.x >> 3);
  const int nbx = N / BN;
  const int bx = wg % nbx, by = wg / nbx;
  const int m0 = by * BM, n0 = bx * BN;

  const int t = threadIdx.x;
  const int w = t >> 6, lane = t & 63;
  const int wr = w >> 2, wc = w & 3;    // wave grid 2 x 4
  const int quad = lane >> 4, c = lane & 15;

  // swizzled ds_read base offsets (byte bit5 ^= row&8; all added bases are
  // multiples of 1024 so the XOR commutes). Verified R4/R5: 0 bank conflicts.
  const int aOff = (((wr * (BM / 2) + c) * 64 + quad * 16) ^ ((c & 8) << 2));
  const int bOff = 2 * AKH + ((((wc * (BN / 4) + c) * 64 + quad * 16) ^ ((c & 8) << 2)));

  // staging: per kh, wave w covers A rows [w*BM/8, +BM/8) and B rows
  // [w*BN/8, +BN/8) in 16-row calls; global col-granule pre-swizzled so the
  // linear global_load_lds dest lands swizzled data.
  const int scol = (((lane & 3) ^ ((lane >> 4) & 2)) << 3);  // elements
  const bf16* gA[NCA];
  const bf16* gB[NCB];
#pragma unroll
  for (int cc = 0; cc < NCA; ++cc)
    gA[cc] = A + (size_t)(m0 + w * (BM / 8) + cc * 16 + (lane >> 2)) * K + scol;
#pragma unroll
  for (int cc = 0; cc < NCB; ++cc)
    gB[cc] = Bt + (size_t)(n0 + w * (BN / 8) + cc * 16 + (lane >> 2)) * K + scol;

  auto stageKh = [&](int P, int kh, int ke) {
    char* ab = lds + P * BUF + kh * AKH + w * (BM * 8);
#pragma unroll
    for (int cc = 0; cc < NCA; ++cc) gld_lds16(gA[cc] + ke, (bf16*)(ab + cc * 1024));
    char* bb = lds + P * BUF + 2 * AKH + kh * BKH + w * (BN * 8);
#pragma unroll
    for (int cc = 0; cc < NCB; ++cc) gld_lds16(gB[cc] + ke, (bf16*)(bb + cc * 1024));
  };

  bf16x8 a0[MF], b0v[NF], a1[MF], b1v[NF];
  auto ldFr = [&](int P, int kh, bf16x8* av, bf16x8* bv) {
    const char* ab = lds + P * BUF + kh * AKH + aOff;
#pragma unroll
    for (int i = 0; i < MF; ++i) av[i] = *(const bf16x8*)(ab + i * 1024);
    const char* bb = lds + P * BUF + kh * BKH + bOff;  // bOff includes 2*AKH
#pragma unroll
    for (int j = 0; j < NF; ++j) bv[j] = *(const bf16x8*)(bb + j * 1024);
  };

  f32x4 acc[MF][NF];
#pragma unroll
  for (int i = 0; i < MF; ++i)
#pragma unroll
    for (int j = 0; j < NF; ++j) acc[i][j] = (f32x4){0.f, 0.f, 0.f, 0.f};

  auto mfmac = [&](bf16x8* av, bf16x8* bv) {
    PRIO1();
#pragma unroll
    for (int i = 0; i < MF; ++i)
#pragma unroll
      for (int j = 0; j < NF; ++j)
        acc[i][j] = __builtin_amdgcn_mfma_f32_16x16x32_bf16(av[i], bv[j], acc[i][j], 0, 0, 0);
    PRIO0();
  };

  auto gtile = [&](int P, bool S0, bool S1) {
    BAR();
    ldFr(P, 0, a0, b0v);
    if (S0) stageKh(P ^ 1, 1, 96);      // t+1's kh1 -> other buffer
    mfmac(a0, b0v);
    ldFr(P, 1, a1, b1v);
    BAR();
    if (S1) stageKh(P, 0, 128);         // t+2's kh0 -> this buffer
    mfmac(a1, b1v);
  };

  auto adv = [&]() {
#pragma unroll
    for (int cc = 0; cc < NCA; ++cc) gA[cc] += 64;
#pragma unroll
    for (int cc = 0; cc < NCB; ++cc) gB[cc] += 64;
  };

  // prologue: tile0 both kh + tile1 kh0; retire tile0's groups (VM4 leaves
  // tile1-kh0's 4 calls in flight)
  stageKh(0, 0, 0); stageKh(0, 1, 32); stageKh(1, 0, 64);
  VM4();

  for (int tt = 0; tt < NT - 2; tt += 2) {
    gtile(0, true, true); VM4(); adv();
    gtile(1, true, true); VM4(); adv();
  }
  gtile(0, true, false); VM0();         // penultimate: stage NT-1's kh1 only
  gtile(1, false, false);               // last: no staging

  // epilogue: C write (verified fragment mapping: row=quad*4+r, col=c)
  const int crow = m0 + wr * (BM / 2) + quad * 4;
  const int ccol = n0 + wc * (BN / 4) + c;
#pragma unroll
  for (int mf = 0; mf < MF; ++mf)
#pragma unroll
    for (int nn = 0; nn < NF; ++nn) {
      const int row = crow + mf * 16;
      const int col = ccol + nn * 16;
      if constexpr (OUT_BF16) {
        bf16* Cp = (bf16*)Cout;
#pragma unroll
        for (int r = 0; r < 4; ++r) Cp[(size_t)(row + r) * N + col] = (bf16)acc[mf][nn][r];
      } else {
        float* Cp = (float*)Cout;
#pragma unroll
        for (int r = 0; r < 4; ++r) Cp[(size_t)(row + r) * N + col] = acc[mf][nn][r];
      }
    }
}

// ---------------- flash attention (causal GQA, transposed-S) ---------------
// R7: grid (qb, bh) -> consecutive blocks share one K/V stream (L2 reuse).
// 8 waves/block, QBLK=128: wave w owns q rows [q0+16w, q0+16w+16).
// K-chunk = 64 keys; staging 32B K + 32B V per thread (T14 reg double-buf).
// lb(512,4) -> <=128 VGPR -> 2 blocks/CU. Wave-uniform skip of the upper
// 32-key half (QK tiles 2,3 + pf1 PV) when fully causally masked.
#define QBLK 128
#define KVB 64
#define SKS 136
#define SVS 72
__global__ __launch_bounds__(512, 4) void attn_kernel(const bf16* __restrict__ q_r,
                                                      const bf16* __restrict__ k_r,
                                                      const bf16* __restrict__ v_t,
                                                      bf16* __restrict__ attn_out) {
  __shared__ bf16 Ks[KVB * SKS];   // [key][d]   64 x (128+8)
  __shared__ bf16 Vs[128 * SVS];   // [d][key]  128 x (64+8)

  const int qb = blockIdx.x, bh = blockIdx.y;   // bh = b*NH + h
  const int b = bh >> 5, h = bh & 31;
  const int kv = h >> 2;               // N_GROUPS = 4
  const int q0 = qb * QBLK;
  const int t = threadIdx.x, w = t >> 6, lane = t & 63;
  const int quad = lane >> 4, c = lane & 15;
  const int myq = q0 + w * 16 + c;     // the q row this lane owns for softmax

  // Q B-frags (B[n=q][k=d]), held in registers across the whole K loop
  const bf16* qrow = q_r + ((size_t)(b * NH + h) * S_ + myq) * HD;
  bf16x8 qf[4];
#pragma unroll
  for (int kk = 0; kk < 4; ++kk) qf[kk] = *(const bf16x8*)(qrow + quad * 8 + kk * 32);

  float m_i = -1e30f, l_i = 0.f;       // per-lane (row = myq)
  f32x4 o_acc[8];
#pragma unroll
  for (int n = 0; n < 8; ++n) o_acc[n] = (f32x4){0.f, 0.f, 0.f, 0.f};

  const bf16* kb_ptr = k_r + (size_t)(b * NKV + kv) * S_ * HD;
  const bf16* vb_ptr = v_t + (size_t)(b * NKV + kv) * HD * S_;

  const int nch = 2 * qb + 2;          // 64-key chunks covering q0+QBLK keys

  // staging (512 threads): K key t>>3, d-granules (t&7)*8 and +64;
  // V d-row t>>2, key-granules (t&3)*16 and +8.
  const int kkey = t >> 3, kg = (t & 7) * 8;
  const int vd = t >> 2, vk = (t & 3) * 16;
  const bf16* kp = kb_ptr + (size_t)kkey * HD + kg;
  const bf16* vp = vb_ptr + (size_t)vd * S_ + vk;

  // P-conversion shuffle sources (per 32-key group): lane (c,quad) pulls key
  // 8q+j from lane c+32*(quad&1) (j<4) / +16 (j>=4); tile select = quad>>1.
  const int src0 = c + 32 * (quad & 1);
  const int src1 = src0 + 16;
  const bool hiTile = (quad & 2) != 0;

  auto packP = [&](const float* ea, const float* eb) -> bf16x8 {
    u32 pk[4];
#pragma unroll
    for (int r = 0; r < 4; ++r) pk[r] = bf16bits(ea[r]) | (bf16bits(eb[r]) << 16);
    u32 a0[4], a1[4];
#pragma unroll
    for (int r = 0; r < 4; ++r) {
      a0[r] = (u32)__shfl((int)pk[r], src0, 64);
      a1[r] = (u32)__shfl((int)pk[r], src1, 64);
    }
    u32 w0, w1, w2, w3;
    if (hiTile) {
      w0 = (a0[0] >> 16) | (a0[1] & 0xffff0000u);
      w1 = (a0[2] >> 16) | (a0[3] & 0xffff0000u);
      w2 = (a1[0] >> 16) | (a1[1] & 0xffff0000u);
      w3 = (a1[2] >> 16) | (a1[3] & 0xffff0000u);
    } else {
      w0 = (a0[0] & 0xffffu) | (a0[1] << 16);
      w1 = (a0[2] & 0xffffu) | (a0[3] << 16);
      w2 = (a1[0] & 0xffffu) | (a1[1] << 16);
      w3 = (a1[2] & 0xffffu) | (a1[3] << 16);
    }
    return __builtin_bit_cast(bf16x8, (u32x4){w0, w1, w2, w3});
  };

  // T14 prologue: chunk 0 -> regs
  bf16x8 krg0 = *(const bf16x8*)(kp);
  bf16x8 krg1 = *(const bf16x8*)(kp + 64);
  bf16x8 vrg0 = *(const bf16x8*)(vp);
  bf16x8 vrg1 = *(const bf16x8*)(vp + 8);

  for (int ch = 0; ch < nch; ++ch) {
    const int kb = ch * KVB;
    __syncthreads();   // previous chunk's LDS reads done before overwrite
    *(bf16x8*)(Ks + kkey * SKS + kg) = krg0;
    *(bf16x8*)(Ks + kkey * SKS + kg + 64) = krg1;
    *(bf16x8*)(Vs + vd * SVS + vk) = vrg0;
    *(bf16x8*)(Vs + vd * SVS + vk + 8) = vrg1;
    if (ch + 1 < nch) {                // issue next chunk's loads (T14)
      kp += (size_t)KVB * HD;
      vp += KVB;
      krg0 = *(const bf16x8*)(kp);
      krg1 = *(const bf16x8*)(kp + 64);
      vrg0 = *(const bf16x8*)(vp);
      vrg1 = *(const bf16x8*)(vp + 8);
    }
    __syncthreads();

    const int wmax = q0 + w * 16 + 15;
    if (kb <= wmax) {                  // wave has at least one unmasked key
      const bool hi = (kb + 32 <= wmax);  // upper 32-key half needed?
      // S^T = K Q^T : 16(key)x16(q) tiles
      f32x4 st0 = (f32x4){0.f, 0.f, 0.f, 0.f};
      f32x4 st1 = (f32x4){0.f, 0.f, 0.f, 0.f};
      f32x4 st2 = (f32x4){0.f, 0.f, 0.f, 0.f};
      f32x4 st3 = (f32x4){0.f, 0.f, 0.f, 0.f};
#pragma unroll
      for (int kk = 0; kk < 4; ++kk) {
        bf16x8 kf0 = *(const bf16x8*)(Ks + (c) * SKS + quad * 8 + kk * 32);
        bf16x8 kf1 = *(const bf16x8*)(Ks + (16 + c) * SKS + quad * 8 + kk * 32);
        st0 = __builtin_amdgcn_mfma_f32_16x16x32_bf16(kf0, qf[kk], st0, 0, 0, 0);
        st1 = __builtin_amdgcn_mfma_f32_16x16x32_bf16(kf1, qf[kk], st1, 0, 0, 0);
      }
      if (hi) {
#pragma unroll
        for (int kk = 0; kk < 4; ++kk) {
          bf16x8 kf2 = *(const bf16x8*)(Ks + (32 + c) * SKS + quad * 8 + kk * 32);
          bf16x8 kf3 = *(const bf16x8*)(Ks + (48 + c) * SKS + quad * 8 + kk * 32);
          st2 = __builtin_amdgcn_mfma_f32_16x16x32_bf16(kf2, qf[kk], st2, 0, 0, 0);
          st3 = __builtin_amdgcn_mfma_f32_16x16x32_bf16(kf3, qf[kk], st3, 0, 0, 0);
        }
      }

      // masking (key of st{kt} reg r = kb + kt*16 + quad*4 + r, row = myq)
      float e0[4], e1[4], e2[4], e3[4];
#pragma unroll
      for (int r = 0; r < 4; ++r) { e0[r] = st0[r]; e1[r] = st1[r]; e2[r] = st2[r]; e3[r] = st3[r]; }
      const int key0 = kb + quad * 4;
      if (kb + 31 > q0 + w * 16) {
#pragma unroll
        for (int r = 0; r < 4; ++r) {
          if (key0 + r > myq) e0[r] = -1e30f;
          if (key0 + 16 + r > myq) e1[r] = -1e30f;
        }
      }
      if (hi && kb + 63 > q0 + w * 16) {
#pragma unroll
        for (int r = 0; r < 4; ++r) {
          if (key0 + 32 + r > myq) e2[r] = -1e30f;
          if (key0 + 48 + r > myq) e3[r] = -1e30f;
        }
      }

      // softmax for row myq: in-reg + 2 shfl across quads
      float mloc = fmaxf(fmaxf(fmaxf(e0[0], e0[1]), fmaxf(e0[2], e0[3])),
                         fmaxf(fmaxf(e1[0], e1[1]), fmaxf(e1[2], e1[3])));
      if (hi)
        mloc = fmaxf(mloc, fmaxf(fmaxf(fmaxf(e2[0], e2[1]), fmaxf(e2[2], e2[3])),
                                 fmaxf(fmaxf(e3[0], e3[1]), fmaxf(e3[2], e3[3]))));
      mloc = fmaxf(mloc, __shfl_xor(mloc, 16, 64));
      mloc = fmaxf(mloc, __shfl_xor(mloc, 32, 64));
      const bool defer = (__all(mloc - m_i <= 8.0f) != 0);  // T13, THR=8
      const float mnew = defer ? m_i : fmaxf(m_i, mloc);
      float sum = 0.f;
#pragma unroll
      for (int r = 0; r < 4; ++r) {
        e0[r] = __expf(e0[r] - mnew); sum += e0[r];
        e1[r] = __expf(e1[r] - mnew); sum += e1[r];
      }
      if (hi) {
#pragma unroll
        for (int r = 0; r < 4; ++r) {
          e2[r] = __expf(e2[r] - mnew); sum += e2[r];
          e3[r] = __expf(e3[r] - mnew); sum += e3[r];
        }
      }
      sum += __shfl_xor(sum, 16, 64);
      sum += __shfl_xor(sum, 32, 64);
      if (!defer) {
        const float alpha = __expf(m_i - mnew);
        m_i = mnew;
        l_i = l_i * alpha + sum;
        float alpha_o[4];
#pragma unroll
        for (int r = 0; r < 4; ++r) alpha_o[r] = __shfl(alpha, quad * 4 + r, 64);
#pragma unroll
        for (int n = 0; n < 8; ++n)
#pragma unroll
          for (int r = 0; r < 4; ++r) o_acc[n][r] *= alpha_o[r];
      } else {
        l_i += sum;
      }

      // P -> MFMA A-layout; O += P V
      bf16x8 pf0 = packP(e0, e1);
#pragma unroll
      for (int n = 0; n < 8; ++n) {
        bf16x8 vf0 = *(const bf16x8*)(Vs + (n * 16 + c) * SVS + quad * 8);
        o_acc[n] = __builtin_amdgcn_mfma_f32_16x16x32_bf16(pf0, vf0, o_acc[n], 0, 0, 0);
      }
      if (hi) {
        bf16x8 pf1 = packP(e2, e3);
#pragma unroll
        for (int n = 0; n < 8; ++n) {
          bf16x8 vf1 = *(const bf16x8*)(Vs + (n * 16 + c) * SVS + 32 + quad * 8);
          o_acc[n] = __builtin_amdgcn_mfma_f32_16x16x32_bf16(pf1, vf1, o_acc[n], 0, 0, 0);
        }
      }
    }
  }

  // epilogue: O /= l (l for row quad*4+r lives at lane quad*4+r), write out
  float l_o[4];
#pragma unroll
  for (int r = 0; r < 4; ++r) l_o[r] = __shfl(l_i, quad * 4 + r, 64);
#pragma unroll
  for (int n = 0; n < 8; ++n)
#pragma unroll
    for (int r = 0; r < 4; ++r) {
      const int row = q0 + w * 16 + quad * 4 + r;
      const float ov = o_acc[n][r] / l_o[r];
      attn_out[((size_t)b * S_ + row) * DM + h * HD + n * 16 + c] = (bf16)ov;
    }
}

// ---------------------------------------------------------------------------
extern "C" void kernel_launch(void* const* d_in, const int* in_sizes, int n_in,
                              void* d_out, int out_size, void* d_ws, size_t ws_size,
                              hipStream_t stream) {
  const float* hidden = (const float*)d_in[0];
  const float* cosT = (const float*)d_in[1];
  const float* sinT = (const float*)d_in[2];
  const float* Wqkv = (const float*)d_in[3];
  const float* Wout = (const float*)d_in[4];
  float* out = (float*)d_out;
  char* ws = (char*)d_ws;

  bf16* WqkvT = (bf16*)(ws + 0);
  bf16* q_r = (bf16*)(ws + 0);
  bf16* k_r = (bf16*)(ws + 33554432);
  bf16* WoutT = (bf16*)(ws + 50331648);
  bf16* h_bf = (bf16*)(ws + 83886080);
  bf16* attn_out = (bf16*)(ws + 83886080);
  bf16* v_t = (bf16*)(ws + 117440512);
  bf16* qkv = (bf16*)d_out;

  static bool attr_set = false;
  if (!attr_set) {
    hipFuncSetAttribute(reinterpret_cast<const void*>(&gemm_bt<true, 128, 384>),
                        hipFuncAttributeMaxDynamicSharedMemorySize, 131072);
    hipFuncSetAttribute(reinterpret_cast<const void*>(&gemm_bt<false, 256, 256>),
                        hipFuncAttributeMaxDynamicSharedMemorySize, 131072);
    attr_set = true;
  }

  cast_f32_bf16<<<dim3(16384), dim3(256), 0, stream>>>(hidden, h_bf, B_ * S_ * DM);
  transpose_cast_w<<<dim3(QKV_DIM / 64, DM / 64), dim3(256), 0, stream>>>(Wqkv, WqkvT, DM, QKV_DIM);
  transpose_cast_w<<<dim3(DM / 64, DM / 64), dim3(256), 0, stream>>>(Wout, WoutT, DM, DM);
  gemm_bt<true, 128, 384><<<dim3((QKV_DIM / 384) * ((B_ * S_) / 128)), dim3(512), 131072, stream>>>(
      h_bf, WqkvT, (void*)qkv, B_ * S_, QKV_DIM, DM);
  rope_kernel<<<dim3(B_ * S_), dim3(320), 0, stream>>>(qkv, cosT, sinT, q_r, k_r);
  transpose_v<<<dim3(S_ / 64, HD / 64, B_ * NKV), dim3(256), 0, stream>>>(qkv, v_t);
  attn_kernel<<<dim3(S_ / QBLK, B_ * NH), dim3(512), 0, stream>>>(q_r, k_r, v_t, attn_out);
  gemm_bt<false, 256, 256><<<dim3((DM / 256) * ((B_ * S_) / 256)), dim3(512), 131072, stream>>>(
      attn_out, WoutT, (void*)out, B_ * S_, DM, DM);
}

// Round 5
// 819.232 us; speedup vs baseline: 1.0120x; 1.0120x over previous
//
#include <hip/hip_runtime.h>

// ---------------------------------------------------------------------------
// GQA attention block: QKV proj -> RoPE -> causal GQA flash attention -> out proj
// B=2 S=2048 D=4096 NH=32 NKV=8 HD=128 (QKV_DIM=6144)
// R8: attention fixed after R7's regression (VGPR clamp -> spill, 8-way LDS
//     conflicts): 4 waves/256thr, QBLK=64, lb(256,2) (no register clamp),
//     unpadded Ks[64][128]/Vs[128][64] with XOR swizzle byte^=((row&7)<<4),
//     staged via global_load_lds with pre-swizzled per-lane global source
//     (linear LDS dest), single 32KiB buffer -> 4 blocks/CU TLP.
//     Kept: in-register softmax, packP, defer-max, diag hi-half skip,
//     (qb,bh) grid for K/V L2 sharing. GEMMs/rope unchanged from R7.
// ---------------------------------------------------------------------------

typedef __bf16 bf16;
typedef bf16 bf16x8 __attribute__((ext_vector_type(8)));
typedef bf16 bf16x4 __attribute__((ext_vector_type(4)));
typedef float f32x4 __attribute__((ext_vector_type(4)));
typedef unsigned int u32;
typedef u32 u32x4 __attribute__((ext_vector_type(4)));

#define B_ 2
#define S_ 2048
#define DM 4096
#define NH 32
#define NKV 8
#define HD 128
#define QKV_DIM 6144

typedef __attribute__((address_space(3))) void lds_void;
typedef const __attribute__((address_space(1))) void glb_void;

__device__ __forceinline__ void gld_lds16(const bf16* g, bf16* l) {
  __builtin_amdgcn_global_load_lds((glb_void*)g, (lds_void*)l, 16, 0, 0);
}

__device__ __forceinline__ u32 bf16bits(float x) {
  union { bf16 h; unsigned short s; } u;
  u.h = (bf16)x;
  return (u32)u.s;
}

#define BAR() __builtin_amdgcn_s_barrier()
#define VM4() asm volatile("s_waitcnt vmcnt(4)" ::: "memory")
#define VM0() asm volatile("s_waitcnt vmcnt(0)" ::: "memory")
#define PRIO1() __builtin_amdgcn_s_setprio(1)
#define PRIO0() __builtin_amdgcn_s_setprio(0)

// ---------------- cast fp32 -> bf16 (hidden states) ----------------
__global__ __launch_bounds__(256) void cast_f32_bf16(const float* __restrict__ src,
                                                     bf16* __restrict__ dst, int n) {
  int i = (blockIdx.x * 256 + threadIdx.x) * 4;
  float4 v = *(const float4*)(src + i);
  bf16x4 o;
  o[0] = (bf16)v.x; o[1] = (bf16)v.y; o[2] = (bf16)v.z; o[3] = (bf16)v.w;
  *(bf16x4*)(dst + i) = o;
}

// ---------------- transpose + cast weights: W[K][N] f32 -> Wt[N][K] bf16 ----
__global__ __launch_bounds__(256) void transpose_cast_w(const float* __restrict__ W,
                                                        bf16* __restrict__ Wt,
                                                        int K, int N) {
  __shared__ float tile[64][65];
  const int n0 = blockIdx.x * 64, k0 = blockIdx.y * 64;
  const int t = threadIdx.x, j = t & 63, i0 = t >> 6;
  for (int p = 0; p < 16; ++p) {
    int i = i0 + p * 4;
    tile[i][j] = W[(size_t)(k0 + i) * N + n0 + j];
  }
  __syncthreads();
  for (int p = 0; p < 16; ++p) {
    int n = i0 + p * 4;
    Wt[(size_t)(n0 + n) * K + k0 + j] = (bf16)tile[j][n];
  }
}

// ---------------- transpose V out of qkv: v_t[b][kv][d][s] ----------------
__global__ __launch_bounds__(256) void transpose_v(const bf16* __restrict__ qkv,
                                                   bf16* __restrict__ v_t) {
  __shared__ bf16 tile[64][65];
  const int s0 = blockIdx.x * 64;
  const int d0 = blockIdx.y * 64;
  const int bk = blockIdx.z;            // b*8+kv
  const int b = bk >> 3, kv = bk & 7;
  const int t = threadIdx.x, j = t & 63, i0 = t >> 6;
  const bf16* src = qkv + (size_t)b * S_ * QKV_DIM + 5120 + kv * HD;  // v offset 5120
  for (int p = 0; p < 16; ++p) {
    int i = i0 + p * 4;
    tile[i][j] = src[(size_t)(s0 + i) * QKV_DIM + d0 + j];
  }
  __syncthreads();
  bf16* dst = v_t + ((size_t)bk * HD + d0) * S_ + s0;
  for (int p = 0; p < 16; ++p) {
    int dd = i0 + p * 4;
    dst[(size_t)dd * S_ + j] = tile[j][dd];
  }
}

// ---------------- RoPE + repack q,k (vectorized; q pre-scaled) -------------
__global__ __launch_bounds__(320) void rope_kernel(const bf16* __restrict__ qkv,
                                                   const float* __restrict__ cosT,
                                                   const float* __restrict__ sinT,
                                                   bf16* __restrict__ q_r,
                                                   bf16* __restrict__ k_r) {
  const int bs = blockIdx.x;            // b*S + s
  const int b = bs >> 11, s = bs & 2047;
  const int t = threadIdx.x;
  const int hh = t >> 3;                // 0..39 (q heads then k heads)
  const int g = (t & 7) * 8;            // lower-half d-granule base
  const bool isQ = hh < NH;
  const bf16* row = qkv + (size_t)bs * QKV_DIM + (isQ ? hh * HD : DM + (hh - NH) * HD);
  bf16x8 xl8 = *(const bf16x8*)(row + g);
  bf16x8 xh8 = *(const bf16x8*)(row + g + 64);
  const float* cbase = cosT + (size_t)s * HD;
  const float* sbase = sinT + (size_t)s * HD;
  float cl[8], sl[8], ch[8], sh[8];
  *(float4*)(cl) = *(const float4*)(cbase + g);
  *(float4*)(cl + 4) = *(const float4*)(cbase + g + 4);
  *(float4*)(ch) = *(const float4*)(cbase + g + 64);
  *(float4*)(ch + 4) = *(const float4*)(cbase + g + 68);
  *(float4*)(sl) = *(const float4*)(sbase + g);
  *(float4*)(sl + 4) = *(const float4*)(sbase + g + 4);
  *(float4*)(sh) = *(const float4*)(sbase + g + 64);
  *(float4*)(sh + 4) = *(const float4*)(sbase + g + 68);
  const float scale = isQ ? 0.08838834764831845f : 1.0f;  // 1/sqrt(128) for q
  bf16x8 ol8, oh8;
#pragma unroll
  for (int j = 0; j < 8; ++j) {
    const float xl = (float)xl8[j], xh = (float)xh8[j];
    ol8[j] = (bf16)((xl * cl[j] - xh * sl[j]) * scale);
    oh8[j] = (bf16)((xh * ch[j] + xl * sh[j]) * scale);
  }
  bf16* dst = isQ ? (q_r + (((size_t)(b * NH + hh)) * S_ + s) * HD)
                  : (k_r + (((size_t)(b * NKV + (hh - NH))) * S_ + s) * HD);
  *(bf16x8*)(dst + g) = ol8;
  *(bf16x8*)(dst + g + 64) = oh8;
}

// ---------------- GEMM: C[M][N] = A[M][K] * Bt[N][K]^T  (BM x BN tiles) -----
// (unchanged from R6/R7 — see comments there)
template <bool OUT_BF16, int BM, int BN>
__global__ __launch_bounds__(512, 2) void gemm_bt(const bf16* __restrict__ A,
                                                  const bf16* __restrict__ Bt,
                                                  void* __restrict__ Cout,
                                                  int M, int N, int K) {
  constexpr int MF = BM / 32;
  constexpr int NF = BN / 64;
  constexpr int NCA = BM / 128;
  constexpr int NCB = BN / 128;
  constexpr int AKH = BM * 64;
  constexpr int BKH = BN * 64;
  constexpr int BUF = 2 * (AKH + BKH);
  extern __shared__ char lds[];
  const int NT = K >> 6;

  const int nwg = gridDim.x;
  const int cpx = nwg >> 3;
  const int wg = (blockIdx.x & 7) * cpx + (blockIdx.x >> 3);
  const int nbx = N / BN;
  const int bx = wg % nbx, by = wg / nbx;
  const int m0 = by * BM, n0 = bx * BN;

  const int t = threadIdx.x;
  const int w = t >> 6, lane = t & 63;
  const int wr = w >> 2, wc = w & 3;
  const int quad = lane >> 4, c = lane & 15;

  const int aOff = (((wr * (BM / 2) + c) * 64 + quad * 16) ^ ((c & 8) << 2));
  const int bOff = 2 * AKH + ((((wc * (BN / 4) + c) * 64 + quad * 16) ^ ((c & 8) << 2)));

  const int scol = (((lane & 3) ^ ((lane >> 4) & 2)) << 3);
  const bf16* gA[NCA];
  const bf16* gB[NCB];
#pragma unroll
  for (int cc = 0; cc < NCA; ++cc)
    gA[cc] = A + (size_t)(m0 + w * (BM / 8) + cc * 16 + (lane >> 2)) * K + scol;
#pragma unroll
  for (int cc = 0; cc < NCB; ++cc)
    gB[cc] = Bt + (size_t)(n0 + w * (BN / 8) + cc * 16 + (lane >> 2)) * K + scol;

  auto stageKh = [&](int P, int kh, int ke) {
    char* ab = lds + P * BUF + kh * AKH + w * (BM * 8);
#pragma unroll
    for (int cc = 0; cc < NCA; ++cc) gld_lds16(gA[cc] + ke, (bf16*)(ab + cc * 1024));
    char* bb = lds + P * BUF + 2 * AKH + kh * BKH + w * (BN * 8);
#pragma unroll
    for (int cc = 0; cc < NCB; ++cc) gld_lds16(gB[cc] + ke, (bf16*)(bb + cc * 1024));
  };

  bf16x8 a0[MF], b0v[NF], a1[MF], b1v[NF];
  auto ldFr = [&](int P, int kh, bf16x8* av, bf16x8* bv) {
    const char* ab = lds + P * BUF + kh * AKH + aOff;
#pragma unroll
    for (int i = 0; i < MF; ++i) av[i] = *(const bf16x8*)(ab + i * 1024);
    const char* bb = lds + P * BUF + kh * BKH + bOff;
#pragma unroll
    for (int j = 0; j < NF; ++j) bv[j] = *(const bf16x8*)(bb + j * 1024);
  };

  f32x4 acc[MF][NF];
#pragma unroll
  for (int i = 0; i < MF; ++i)
#pragma unroll
    for (int j = 0; j < NF; ++j) acc[i][j] = (f32x4){0.f, 0.f, 0.f, 0.f};

  auto mfmac = [&](bf16x8* av, bf16x8* bv) {
    PRIO1();
#pragma unroll
    for (int i = 0; i < MF; ++i)
#pragma unroll
      for (int j = 0; j < NF; ++j)
        acc[i][j] = __builtin_amdgcn_mfma_f32_16x16x32_bf16(av[i], bv[j], acc[i][j], 0, 0, 0);
    PRIO0();
  };

  auto gtile = [&](int P, bool S0, bool S1) {
    BAR();
    ldFr(P, 0, a0, b0v);
    if (S0) stageKh(P ^ 1, 1, 96);
    mfmac(a0, b0v);
    ldFr(P, 1, a1, b1v);
    BAR();
    if (S1) stageKh(P, 0, 128);
    mfmac(a1, b1v);
  };

  auto adv = [&]() {
#pragma unroll
    for (int cc = 0; cc < NCA; ++cc) gA[cc] += 64;
#pragma unroll
    for (int cc = 0; cc < NCB; ++cc) gB[cc] += 64;
  };

  stageKh(0, 0, 0); stageKh(0, 1, 32); stageKh(1, 0, 64);
  VM4();

  for (int tt = 0; tt < NT - 2; tt += 2) {
    gtile(0, true, true); VM4(); adv();
    gtile(1, true, true); VM4(); adv();
  }
  gtile(0, true, false); VM0();
  gtile(1, false, false);

  const int crow = m0 + wr * (BM / 2) + quad * 4;
  const int ccol = n0 + wc * (BN / 4) + c;
#pragma unroll
  for (int mf = 0; mf < MF; ++mf)
#pragma unroll
    for (int nn = 0; nn < NF; ++nn) {
      const int row = crow + mf * 16;
      const int col = ccol + nn * 16;
      if constexpr (OUT_BF16) {
        bf16* Cp = (bf16*)Cout;
#pragma unroll
        for (int r = 0; r < 4; ++r) Cp[(size_t)(row + r) * N + col] = (bf16)acc[mf][nn][r];
      } else {
        float* Cp = (float*)Cout;
#pragma unroll
        for (int r = 0; r < 4; ++r) Cp[(size_t)(row + r) * N + col] = acc[mf][nn][r];
      }
    }
}

// ---------------- flash attention (causal GQA, transposed-S) ---------------
// R8: 4 waves/256thr, QBLK=64, wave w owns q rows [q0+16w, +16). KVB=64.
// Ks[64][128] / Vs[128][64] bf16, unpadded, XOR-swizzled byte^=((row&7)<<4);
// staged by global_load_lds with pre-swizzled per-lane global source (linear
// LDS dest). Single buffer: stage; vmcnt0+bar; compute; bar. Swizzled b128
// fragment reads are uniform 8 lanes/16B-slot -> conflict-free.
// grid (qb, bh): consecutive blocks share one K/V stream (L2 reuse).
#define QBLK 64
#define KVB 64
__global__ __launch_bounds__(256, 2) void attn_kernel(const bf16* __restrict__ q_r,
                                                      const bf16* __restrict__ k_r,
                                                      const bf16* __restrict__ v_t,
                                                      bf16* __restrict__ attn_out) {
  __shared__ bf16 Ks[KVB * HD];    // [key][d]  64x128, swizzled
  __shared__ bf16 Vs[HD * KVB];    // [d][key] 128x64,  swizzled

  const int qb = blockIdx.x, bh = blockIdx.y;   // bh = b*NH + h
  const int b = bh >> 5, h = bh & 31;
  const int kv = h >> 2;               // N_GROUPS = 4
  const int q0 = qb * QBLK;
  const int t = threadIdx.x, w = t >> 6, lane = t & 63;
  const int quad = lane >> 4, c = lane & 15;
  const int myq = q0 + w * 16 + c;     // the q row this lane owns for softmax

  // Q B-frags (B[n=q][k=d]), held in registers across the whole K loop
  const bf16* qrow = q_r + ((size_t)(b * NH + h) * S_ + myq) * HD;
  bf16x8 qf[4];
#pragma unroll
  for (int kk = 0; kk < 4; ++kk) qf[kk] = *(const bf16x8*)(qrow + quad * 8 + kk * 32);

  float m_i = -1e30f, l_i = 0.f;       // per-lane (row = myq)
  f32x4 o_acc[8];
#pragma unroll
  for (int n = 0; n < 8; ++n) o_acc[n] = (f32x4){0.f, 0.f, 0.f, 0.f};

  const bf16* kb_ptr = k_r + (size_t)(b * NKV + kv) * S_ * HD;
  const bf16* vb_ptr = v_t + (size_t)(b * NKV + kv) * HD * S_;
  const int nch = qb + 1;              // 64-key chunks

  // ---- staging source lane offsets (pre-swizzled, elems) ----
  // K: wave w, call j (4 rows/call): row = w*16 + j*4 + lr; lane writes LDS
  //    byte 16*lane -> col byte 16*lc; source col = (16*lc) ^ ((row&7)<<4).
  const int lr = lane >> 4, lc = lane & 15;
  const int kcol0 = (((lc << 4) ^ (lr << 4)) >> 1);        // j even: row&7 = lr
  const int kcol1 = (((lc << 4) ^ ((lr + 4) << 4)) >> 1);  // j odd:  row&7 = lr+4
  // V: wave w, call j (8 rows/call): d = w*32 + j*8 + vlr; col = 16*vlc bytes
  const int vlr = lane >> 3, vlc = lane & 7;
  const int vcol = (((vlc << 4) ^ (vlr << 4)) >> 1);
  // fragment-read XOR (elems)
  const int fxor = (c & 7) << 3;

  // P-conversion shuffle sources (per 32-key group)
  const int src0 = c + 32 * (quad & 1);
  const int src1 = src0 + 16;
  const bool hiTile = (quad & 2) != 0;

  auto packP = [&](const float* ea, const float* eb) -> bf16x8 {
    u32 pk[4];
#pragma unroll
    for (int r = 0; r < 4; ++r) pk[r] = bf16bits(ea[r]) | (bf16bits(eb[r]) << 16);
    u32 a0[4], a1[4];
#pragma unroll
    for (int r = 0; r < 4; ++r) {
      a0[r] = (u32)__shfl((int)pk[r], src0, 64);
      a1[r] = (u32)__shfl((int)pk[r], src1, 64);
    }
    u32 w0, w1, w2, w3;
    if (hiTile) {
      w0 = (a0[0] >> 16) | (a0[1] & 0xffff0000u);
      w1 = (a0[2] >> 16) | (a0[3] & 0xffff0000u);
      w2 = (a1[0] >> 16) | (a1[1] & 0xffff0000u);
      w3 = (a1[2] >> 16) | (a1[3] & 0xffff0000u);
    } else {
      w0 = (a0[0] & 0xffffu) | (a0[1] << 16);
      w1 = (a0[2] & 0xffffu) | (a0[3] << 16);
      w2 = (a1[0] & 0xffffu) | (a1[1] << 16);
      w3 = (a1[2] & 0xffffu) | (a1[3] << 16);
    }
    return __builtin_bit_cast(bf16x8, (u32x4){w0, w1, w2, w3});
  };

  for (int ch = 0; ch < nch; ++ch) {
    const int kb = ch * KVB;
    // stage chunk via global_load_lds (previous compute's reads done: BAR at
    // end of previous iteration)
#pragma unroll
    for (int j = 0; j < 4; ++j) {
      const bf16* gk = kb_ptr + (size_t)(kb + w * 16 + j * 4 + lr) * HD +
                       ((j & 1) ? kcol1 : kcol0);
      gld_lds16(gk, Ks + (w * 16 + j * 4) * HD);
      const bf16* gv = vb_ptr + (size_t)(w * 32 + j * 8 + vlr) * S_ + kb + vcol;
      gld_lds16(gv, Vs + (w * 32 + j * 8) * KVB);
    }
    VM0();
    BAR();

    const int wmax = q0 + w * 16 + 15;
    if (kb <= wmax) {                  // wave has at least one unmasked key
      const bool hi = (kb + 32 <= wmax);  // upper 32-key half needed?
      f32x4 st0 = (f32x4){0.f, 0.f, 0.f, 0.f};
      f32x4 st1 = (f32x4){0.f, 0.f, 0.f, 0.f};
      f32x4 st2 = (f32x4){0.f, 0.f, 0.f, 0.f};
      f32x4 st3 = (f32x4){0.f, 0.f, 0.f, 0.f};
#pragma unroll
      for (int kk = 0; kk < 4; ++kk) {
        const int kx = (quad * 8 + kk * 32) ^ fxor;
        bf16x8 kf0 = *(const bf16x8*)(Ks + (c)*HD + kx);
        bf16x8 kf1 = *(const bf16x8*)(Ks + (16 + c) * HD + kx);
        st0 = __builtin_amdgcn_mfma_f32_16x16x32_bf16(kf0, qf[kk], st0, 0, 0, 0);
        st1 = __builtin_amdgcn_mfma_f32_16x16x32_bf16(kf1, qf[kk], st1, 0, 0, 0);
      }
      if (hi) {
#pragma unroll
        for (int kk = 0; kk < 4; ++kk) {
          const int kx = (quad * 8 + kk * 32) ^ fxor;
          bf16x8 kf2 = *(const bf16x8*)(Ks + (32 + c) * HD + kx);
          bf16x8 kf3 = *(const bf16x8*)(Ks + (48 + c) * HD + kx);
          st2 = __builtin_amdgcn_mfma_f32_16x16x32_bf16(kf2, qf[kk], st2, 0, 0, 0);
          st3 = __builtin_amdgcn_mfma_f32_16x16x32_bf16(kf3, qf[kk], st3, 0, 0, 0);
        }
      }

      float e0[4], e1[4], e2[4], e3[4];
#pragma unroll
      for (int r = 0; r < 4; ++r) { e0[r] = st0[r]; e1[r] = st1[r]; e2[r] = st2[r]; e3[r] = st3[r]; }
      const int key0 = kb + quad * 4;
      if (kb + 31 > q0 + w * 16) {
#pragma unroll
        for (int r = 0; r < 4; ++r) {
          if (key0 + r > myq) e0[r] = -1e30f;
          if (key0 + 16 + r > myq) e1[r] = -1e30f;
        }
      }
      if (hi && kb + 63 > q0 + w * 16) {
#pragma unroll
        for (int r = 0; r < 4; ++r) {
          if (key0 + 32 + r > myq) e2[r] = -1e30f;
          if (key0 + 48 + r > myq) e3[r] = -1e30f;
        }
      }

      float mloc = fmaxf(fmaxf(fmaxf(e0[0], e0[1]), fmaxf(e0[2], e0[3])),
                         fmaxf(fmaxf(e1[0], e1[1]), fmaxf(e1[2], e1[3])));
      if (hi)
        mloc = fmaxf(mloc, fmaxf(fmaxf(fmaxf(e2[0], e2[1]), fmaxf(e2[2], e2[3])),
                                 fmaxf(fmaxf(e3[0], e3[1]), fmaxf(e3[2], e3[3]))));
      mloc = fmaxf(mloc, __shfl_xor(mloc, 16, 64));
      mloc = fmaxf(mloc, __shfl_xor(mloc, 32, 64));
      const bool defer = (__all(mloc - m_i <= 8.0f) != 0);  // T13, THR=8
      const float mnew = defer ? m_i : fmaxf(m_i, mloc);
      float sum = 0.f;
#pragma unroll
      for (int r = 0; r < 4; ++r) {
        e0[r] = __expf(e0[r] - mnew); sum += e0[r];
        e1[r] = __expf(e1[r] - mnew); sum += e1[r];
      }
      if (hi) {
#pragma unroll
        for (int r = 0; r < 4; ++r) {
          e2[r] = __expf(e2[r] - mnew); sum += e2[r];
          e3[r] = __expf(e3[r] - mnew); sum += e3[r];
        }
      }
      sum += __shfl_xor(sum, 16, 64);
      sum += __shfl_xor(sum, 32, 64);
      if (!defer) {
        const float alpha = __expf(m_i - mnew);
        m_i = mnew;
        l_i = l_i * alpha + sum;
        float alpha_o[4];
#pragma unroll
        for (int r = 0; r < 4; ++r) alpha_o[r] = __shfl(alpha, quad * 4 + r, 64);
#pragma unroll
        for (int n = 0; n < 8; ++n)
#pragma unroll
          for (int r = 0; r < 4; ++r) o_acc[n][r] *= alpha_o[r];
      } else {
        l_i += sum;
      }

      // P -> MFMA A-layout; O += P V (swizzled V reads)
      bf16x8 pf0 = packP(e0, e1);
#pragma unroll
      for (int n = 0; n < 8; ++n) {
        bf16x8 vf0 = *(const bf16x8*)(Vs + (n * 16 + c) * KVB + ((quad * 8) ^ fxor));
        o_acc[n] = __builtin_amdgcn_mfma_f32_16x16x32_bf16(pf0, vf0, o_acc[n], 0, 0, 0);
      }
      if (hi) {
        bf16x8 pf1 = packP(e2, e3);
#pragma unroll
        for (int n = 0; n < 8; ++n) {
          bf16x8 vf1 = *(const bf16x8*)(Vs + (n * 16 + c) * KVB + ((quad * 8 + 32) ^ fxor));
          o_acc[n] = __builtin_amdgcn_mfma_f32_16x16x32_bf16(pf1, vf1, o_acc[n], 0, 0, 0);
        }
      }
    }
    BAR();   // all reads done before next chunk's staging overwrites
  }

  // epilogue: O /= l (l for row quad*4+r lives at lane quad*4+r), write out
  float l_o[4];
#pragma unroll
  for (int r = 0; r < 4; ++r) l_o[r] = __shfl(l_i, quad * 4 + r, 64);
#pragma unroll
  for (int n = 0; n < 8; ++n)
#pragma unroll
    for (int r = 0; r < 4; ++r) {
      const int row = q0 + w * 16 + quad * 4 + r;
      const float ov = o_acc[n][r] / l_o[r];
      attn_out[((size_t)b * S_ + row) * DM + h * HD + n * 16 + c] = (bf16)ov;
    }
}

// ---------------------------------------------------------------------------
extern "C" void kernel_launch(void* const* d_in, const int* in_sizes, int n_in,
                              void* d_out, int out_size, void* d_ws, size_t ws_size,
                              hipStream_t stream) {
  const float* hidden = (const float*)d_in[0];
  const float* cosT = (const float*)d_in[1];
  const float* sinT = (const float*)d_in[2];
  const float* Wqkv = (const float*)d_in[3];
  const float* Wout = (const float*)d_in[4];
  float* out = (float*)d_out;
  char* ws = (char*)d_ws;

  bf16* WqkvT = (bf16*)(ws + 0);
  bf16* q_r = (bf16*)(ws + 0);
  bf16* k_r = (bf16*)(ws + 33554432);
  bf16* WoutT = (bf16*)(ws + 50331648);
  bf16* h_bf = (bf16*)(ws + 83886080);
  bf16* attn_out = (bf16*)(ws + 83886080);
  bf16* v_t = (bf16*)(ws + 117440512);
  bf16* qkv = (bf16*)d_out;

  static bool attr_set = false;
  if (!attr_set) {
    hipFuncSetAttribute(reinterpret_cast<const void*>(&gemm_bt<true, 128, 384>),
                        hipFuncAttributeMaxDynamicSharedMemorySize, 131072);
    hipFuncSetAttribute(reinterpret_cast<const void*>(&gemm_bt<false, 256, 256>),
                        hipFuncAttributeMaxDynamicSharedMemorySize, 131072);
    attr_set = true;
  }

  cast_f32_bf16<<<dim3(16384), dim3(256), 0, stream>>>(hidden, h_bf, B_ * S_ * DM);
  transpose_cast_w<<<dim3(QKV_DIM / 64, DM / 64), dim3(256), 0, stream>>>(Wqkv, WqkvT, DM, QKV_DIM);
  transpose_cast_w<<<dim3(DM / 64, DM / 64), dim3(256), 0, stream>>>(Wout, WoutT, DM, DM);
  gemm_bt<true, 128, 384><<<dim3((QKV_DIM / 384) * ((B_ * S_) / 128)), dim3(512), 131072, stream>>>(
      h_bf, WqkvT, (void*)qkv, B_ * S_, QKV_DIM, DM);
  rope_kernel<<<dim3(B_ * S_), dim3(320), 0, stream>>>(qkv, cosT, sinT, q_r, k_r);
  transpose_v<<<dim3(S_ / 64, HD / 64, B_ * NKV), dim3(256), 0, stream>>>(qkv, v_t);
  attn_kernel<<<dim3(S_ / QBLK, B_ * NH), dim3(256), 0, stream>>>(q_r, k_r, v_t, attn_out);
  gemm_bt<false, 256, 256><<<dim3((DM / 256) * ((B_ * S_) / 256)), dim3(512), 131072, stream>>>(
      attn_out, WoutT, (void*)out, B_ * S_, DM, DM);
}